// Round 5
// baseline (215.870 us; speedup 1.0000x reference)
//
#include <hip/hip_runtime.h>
#include <math.h>

// Problem constants (B=8192 rows, D=256 features)
#define NB 8192
#define ND 256

using bf16x8 = __attribute__((ext_vector_type(8))) short;  // 8 bf16 in 4 VGPRs
using f32x4  = __attribute__((ext_vector_type(4))) float;  // MFMA C/D frag

#define POS2 0.99998000f   // (1 - 1e-5)^2, pos_mask_ threshold in d2 space
#define F_INF  __int_as_float(0x7f800000)
#define F_NINF __int_as_float(0xff800000)

__device__ __forceinline__ unsigned short f2bf(float x) {  // RNE fp32->bf16
    unsigned u = __float_as_uint(x);
    return (unsigned short)((u + 0x7fffu + ((u >> 16) & 1u)) >> 16);
}
__device__ __forceinline__ float bf2f(unsigned short b) {
    return __uint_as_float(((unsigned)b) << 16);
}

// async global->LDS, 16 B per lane; LDS dest = wave-uniform base + lane*16
__device__ __forceinline__ void gload_lds16(const unsigned short* g,
                                            unsigned short* l) {
    __builtin_amdgcn_global_load_lds(
        (const __attribute__((address_space(1))) void*)g,
        (__attribute__((address_space(3))) void*)l, 16, 0, 0);
}

// ------------------------------------------- normalize (+ init folded in)
__global__ void normalize_kernel(const float* __restrict__ feats,
                                 unsigned short* __restrict__ fnb,
                                 float* __restrict__ sq,
                                 float* minpos_d2, float* maxneg_d2,
                                 float* negsum, float* possum, float* poscnt,
                                 float* out) {
    int row = blockIdx.x * 4 + (threadIdx.x >> 6);
    int lane = threadIdx.x & 63;
    float4 v = ((const float4*)(feats + (size_t)row * ND))[lane];
    float s = v.x*v.x + v.y*v.y + v.z*v.z + v.w*v.w;
    #pragma unroll
    for (int off = 32; off > 0; off >>= 1) s += __shfl_xor(s, off, 64);
    float inv = 1.0f / (sqrtf(s) + 1e-12f);
    ushort4 w;
    w.x = f2bf(v.x * inv); w.y = f2bf(v.y * inv);
    w.z = f2bf(v.z * inv); w.w = f2bf(v.w * inv);
    ((ushort4*)(fnb + (size_t)row * ND))[lane] = w;
    float ax = bf2f(w.x), ay = bf2f(w.y), az = bf2f(w.z), aw = bf2f(w.w);
    float s2 = ax*ax + ay*ay + az*az + aw*aw;
    #pragma unroll
    for (int off = 32; off > 0; off >>= 1) s2 += __shfl_xor(s2, off, 64);
    if (lane == 0) sq[row] = s2;
    if (lane == 1) {                 // init per-row accumulators
        minpos_d2[row] = F_INF;
        maxneg_d2[row] = F_NINF;
        negsum[row] = 0.f; possum[row] = 0.f; poscnt[row] = 0.f;
    }
    if (blockIdx.x == 0 && threadIdx.x == 0) out[0] = 0.f;
}

// ---------------------------------------------------- fused MFMA passes
// WG tile: 64 i-rows x 1024 j-cols (8 j-tiles of 128). A fragments for the
// wave's 32 rows x full K=256 live in REGISTERS (af[2][8], 64 VGPRs),
// loaded from global in the preamble. B is staged full-K per j-tile
// (128x256 bf16 = 64 KB) via global_load_lds with the XOR swizzle applied
// on the global-address side -> ONE barrier pair per j-tile (16/WG).
// Stats accumulate in registers across the whole j-chunk; one
// reduce+atomic set per WG. grid = (8 j-chunks, 128 i-tiles): linear%8 =
// j-chunk -> per-XCD L2 holds one B slab.
template <int PASS>
__global__ __launch_bounds__(256, 2) void pass_kernel(
    const unsigned short* __restrict__ fnb, const float* __restrict__ sq,
    const int* __restrict__ labels,
    float* __restrict__ minpos_d2, float* __restrict__ maxneg_d2,
    float* __restrict__ negsum, float* __restrict__ possum,
    float* __restrict__ poscnt)
{
    __shared__ __align__(16) unsigned short Bs[128 * 256];  // 64 KB, full K

    const int tid  = threadIdx.x;
    const int lane = tid & 63;
    const int wid  = tid >> 6;
    const int wm   = wid >> 1;       // wave row (0..1) -> 32 i-rows
    const int wn   = wid & 1;        // wave col (0..1) -> 64 j-cols
    const int q    = lane >> 4;
    const int c16  = lane & 15;
    const int i0    = blockIdx.y * 64;
    const int jbase = blockIdx.x * 1024;

    // ---- A fragments -> registers (A layout: [m=lane&15][k=q*8+j]) ----
    bf16x8 af[2][8];
    #pragma unroll
    for (int mt = 0; mt < 2; ++mt) {
        const unsigned short* arow =
            fnb + (size_t)(i0 + wm * 32 + mt * 16 + c16) * ND;
        #pragma unroll
        for (int kb = 0; kb < 8; ++kb)
            af[mt][kb] = *(const bf16x8*)(arow + kb * 32 + q * 8);
    }

    // ---- per-lane i-row invariants (8 rows: (k>>2)*16 + q*4 + (k&3)) ----
    int   labi[8]; float sqi[8];
    float mnd2[8], mxd2[8];          // pass 1 accumulators
    float tneg[8], tpos[8];          // pass 2 thresholds (d2 space)
    float ns[8], ps[8], pc[8];       // pass 2 accumulators
    #pragma unroll
    for (int k = 0; k < 8; ++k) {
        int i = i0 + wm * 32 + (k >> 2) * 16 + q * 4 + (k & 3);
        labi[k] = labels[i];
        sqi[k]  = sq[i];
        if (PASS == 1) {
            mnd2[k] = F_INF; mxd2[k] = F_NINF;
        } else {
            float mp = sqrtf(fmaxf(minpos_d2[i], 1e-12f));
            float tn = mp - 0.1f;
            tneg[k] = (tn <= 0.f) ? -3.0f : tn * tn;        // d2 > tneg
            float mx = sqrtf(fmaxf(maxneg_d2[i], 1e-12f));
            float tp = mx + 0.1f;
            tpos[k] = fminf(tp * tp, POS2);                 // d2 < tpos
            ns[k] = 0.f; ps[k] = 0.f; pc[k] = 0.f;
        }
    }

    for (int jt = 0; jt < 8; ++jt) {
        const int j0 = jbase + jt * 128;

        __syncthreads();   // previous j-tile's Bs readers done
        // stage B full-K, async: wave w covers rows [w*32, w*32+32);
        // inst t: 2 rows (1 KB). lane l: row rb+(l>>5), slot sc=l&31 holds
        // global chunk (sc&24)|((sc^r)&7)  (16-B chunks, 32 per 512-B row)
        #pragma unroll
        for (int t = 0; t < 16; ++t) {
            int rb = wid * 32 + t * 2;
            int r  = rb + (lane >> 5);
            int sc = lane & 31;
            int c  = (sc & 24) | ((sc ^ r) & 7);
            gload_lds16(fnb + (size_t)(j0 + r) * ND + c * 8, Bs + rb * 256);
        }

        int labj[4]; float sqj[4];
        #pragma unroll
        for (int nt = 0; nt < 4; ++nt) {
            int j = j0 + wn * 64 + nt * 16 + c16;
            labj[nt] = labels[j];
            sqj[nt]  = sq[j];
        }

        __syncthreads();   // vmcnt drain + barrier: Bs ready

        f32x4 acc[2][4];
        #pragma unroll
        for (int mt = 0; mt < 2; ++mt)
            #pragma unroll
            for (int nt = 0; nt < 4; ++nt)
                acc[mt][nt] = (f32x4){0.f, 0.f, 0.f, 0.f};

        #pragma unroll
        for (int kb = 0; kb < 8; ++kb) {
            bf16x8 bfr[4];
            #pragma unroll
            for (int nt = 0; nt < 4; ++nt) {
                int r  = wn * 64 + nt * 16 + c16;
                int c  = kb * 4 + q;
                int sc = (c & 24) | ((c ^ r) & 7);
                bfr[nt] = *(const bf16x8*)(Bs + r * 256 + sc * 8);
            }
            #pragma unroll
            for (int mt = 0; mt < 2; ++mt)
                #pragma unroll
                for (int nt = 0; nt < 4; ++nt)
                    acc[mt][nt] = __builtin_amdgcn_mfma_f32_16x16x32_bf16(
                        af[mt][kb], bfr[nt], acc[mt][nt], 0, 0, 0);
        }

        // ---- per-tile epilogue: accumulate into register stats ----
        #pragma unroll
        for (int mt = 0; mt < 2; ++mt) {
            #pragma unroll
            for (int reg = 0; reg < 4; ++reg) {
                int k = mt * 4 + reg;
                #pragma unroll
                for (int nt = 0; nt < 4; ++nt) {
                    float dot = acc[mt][nt][reg];
                    float d2  = fmaf(-2.0f, dot, sqi[k] + sqj[nt]);
                    bool same = (labi[k] == labj[nt]);
                    if (PASS == 1) {
                        bool p = same && (d2 < POS2);
                        mnd2[k] = fminf(mnd2[k], p ? d2 : F_INF);
                        mxd2[k] = fmaxf(mxd2[k], same ? F_NINF : d2);
                    } else {
                        float dist = sqrtf(fmaxf(d2, 1e-12f));
                        bool tkp = same && (d2 < tpos[k]);
                        bool tkn = !same && (d2 > tneg[k]);
                        float arg = fmaf(same ? 2.0f : -40.0f, dist,
                                         same ? -1.4f : 40.0f);
                        float e = __expf(arg);
                        ps[k] += tkp ? e : 0.f;
                        ns[k] += tkn ? e : 0.f;
                        pc[k] += tkp ? 1.f : 0.f;
                    }
                }
            }
        }
    }

    // ---- once per WG: reduce across the 16 c16 lanes, then atomics ----
    #pragma unroll
    for (int k = 0; k < 8; ++k) {
        int i = i0 + wm * 32 + (k >> 2) * 16 + q * 4 + (k & 3);
        if (PASS == 1) {
            #pragma unroll
            for (int off = 8; off > 0; off >>= 1) {
                mnd2[k] = fminf(mnd2[k], __shfl_xor(mnd2[k], off, 64));
                mxd2[k] = fmaxf(mxd2[k], __shfl_xor(mxd2[k], off, 64));
            }
            if (c16 == 0) {
                // at most one sub-zero candidate per row (the diagonal),
                // so int ordering == float ordering for the winner
                atomicMin((int*)&minpos_d2[i], __float_as_int(mnd2[k]));
                atomicMax((int*)&maxneg_d2[i], __float_as_int(mxd2[k]));
            }
        } else {
            #pragma unroll
            for (int off = 8; off > 0; off >>= 1) {
                ns[k] += __shfl_xor(ns[k], off, 64);
                ps[k] += __shfl_xor(ps[k], off, 64);
                pc[k] += __shfl_xor(pc[k], off, 64);
            }
            if (c16 == 0) {
                atomicAdd(&negsum[i], ns[k]);
                atomicAdd(&possum[i], ps[k]);
                atomicAdd(&poscnt[i], pc[k]);
            }
        }
    }
}

// ------------------------------------------------------------- finalize
__global__ void finalize_kernel(const float* __restrict__ negsum,
                                const float* __restrict__ possum,
                                const float* __restrict__ poscnt,
                                float* out) {
    int i = blockIdx.x * 256 + threadIdx.x;
    float v = 0.f;
    if (i < NB) {
        // each neg term >= e^-40 > 0, so negsum>0 <=> neg count >= 1
        bool valid = (negsum[i] > 0.f) && (poscnt[i] >= 0.5f);
        if (valid) {
            float nl = log1pf(negsum[i]) * (1.0f / 40.0f);
            float pl = log1pf(possum[i]) / (poscnt[i] + 1e-5f);
            v = nl + pl;
        }
    }
    #pragma unroll
    for (int off = 32; off > 0; off >>= 1) v += __shfl_xor(v, off, 64);
    __shared__ float red[4];
    if ((threadIdx.x & 63) == 0) red[threadIdx.x >> 6] = v;
    __syncthreads();
    if (threadIdx.x == 0)
        atomicAdd(out, (red[0] + red[1] + red[2] + red[3]) * (1.0f / NB));
}

// ------------------------------------------------------------ launcher
extern "C" void kernel_launch(void* const* d_in, const int* in_sizes, int n_in,
                              void* d_out, int out_size, void* d_ws, size_t ws_size,
                              hipStream_t stream) {
    const float* feats  = (const float*)d_in[0];
    const int*   labels = (const int*)d_in[1];
    float* out = (float*)d_out;

    // workspace: fnb bf16[NB*ND] (4 MB) then fp32 row arrays
    unsigned short* fnb = (unsigned short*)d_ws;
    float* sqv       = (float*)(fnb + (size_t)NB * ND);
    float* minpos_d2 = sqv + NB;
    float* maxneg_d2 = minpos_d2 + NB;
    float* negsum    = maxneg_d2 + NB;
    float* possum    = negsum + NB;
    float* poscnt    = possum + NB;

    normalize_kernel<<<NB / 4, 256, 0, stream>>>(feats, fnb, sqv, minpos_d2,
                                                 maxneg_d2, negsum, possum,
                                                 poscnt, out);

    dim3 grid(NB / 1024, NB / 64);   // (8 j-chunks, 128 i-tiles)
    pass_kernel<1><<<grid, 256, 0, stream>>>(fnb, sqv, labels, minpos_d2,
                                             maxneg_d2, negsum, possum, poscnt);
    pass_kernel<2><<<grid, 256, 0, stream>>>(fnb, sqv, labels, minpos_d2,
                                             maxneg_d2, negsum, possum, poscnt);
    finalize_kernel<<<NB / 256, 256, 0, stream>>>(negsum, possum, poscnt, out);
}

// Round 6
// 211.193 us; speedup vs baseline: 1.0221x; 1.0221x over previous
//
#include <hip/hip_runtime.h>
#include <math.h>

// Problem constants (B=8192 rows, D=256 features)
#define NB 8192
#define ND 256

using bf16x8 = __attribute__((ext_vector_type(8))) short;  // 8 bf16 in 4 VGPRs
using f32x4  = __attribute__((ext_vector_type(4))) float;  // MFMA C/D frag

#define POS2 0.99998000f   // (1 - 1e-5)^2, pos_mask_ threshold in d2 space
#define F_INF  __int_as_float(0x7f800000)
#define F_NINF __int_as_float(0xff800000)

__device__ __forceinline__ unsigned short f2bf(float x) {  // RNE fp32->bf16
    unsigned u = __float_as_uint(x);
    return (unsigned short)((u + 0x7fffu + ((u >> 16) & 1u)) >> 16);
}
__device__ __forceinline__ float bf2f(unsigned short b) {
    return __uint_as_float(((unsigned)b) << 16);
}

// async global->LDS, 16 B per lane; LDS dest = wave-uniform base + lane*16
__device__ __forceinline__ void gload_lds16(const unsigned short* g,
                                            unsigned short* l) {
    __builtin_amdgcn_global_load_lds(
        (const __attribute__((address_space(1))) void*)g,
        (__attribute__((address_space(3))) void*)l, 16, 0, 0);
}

// ------------------------------------------- normalize (+ init folded in)
__global__ void normalize_kernel(const float* __restrict__ feats,
                                 unsigned short* __restrict__ fnb,
                                 float* __restrict__ sq,
                                 float* minpos_d2, float* maxneg_d2,
                                 float* negsum, float* possum, float* poscnt,
                                 float* out) {
    int row = blockIdx.x * 4 + (threadIdx.x >> 6);
    int lane = threadIdx.x & 63;
    float4 v = ((const float4*)(feats + (size_t)row * ND))[lane];
    float s = v.x*v.x + v.y*v.y + v.z*v.z + v.w*v.w;
    #pragma unroll
    for (int off = 32; off > 0; off >>= 1) s += __shfl_xor(s, off, 64);
    float inv = 1.0f / (sqrtf(s) + 1e-12f);
    ushort4 w;
    w.x = f2bf(v.x * inv); w.y = f2bf(v.y * inv);
    w.z = f2bf(v.z * inv); w.w = f2bf(v.w * inv);
    ((ushort4*)(fnb + (size_t)row * ND))[lane] = w;
    float ax = bf2f(w.x), ay = bf2f(w.y), az = bf2f(w.z), aw = bf2f(w.w);
    float s2 = ax*ax + ay*ay + az*az + aw*aw;
    #pragma unroll
    for (int off = 32; off > 0; off >>= 1) s2 += __shfl_xor(s2, off, 64);
    if (lane == 0) sq[row] = s2;
    if (lane == 1) {                 // init per-row accumulators
        minpos_d2[row] = F_INF;
        maxneg_d2[row] = F_NINF;
        negsum[row] = 0.f; possum[row] = 0.f; poscnt[row] = 0.f;
    }
    if (blockIdx.x == 0 && threadIdx.x == 0) out[0] = 0.f;
}

// ---------------------------------------------------- fused MFMA passes
// WG tile: 64 i-rows x 1024 j-cols (8 j-tiles of 128). A fragments live in
// REGISTERS (af[2][8], 64 VGPRs). B is staged in BK=128 chunks (32 KB) into
// a 2-buffer ping-pong via global_load_lds; every __syncthreads drains
// loads that were issued one full compute-phase earlier, so the vmcnt(0)
// drain has a latency shadow (the round-5 kernel had none).
// Chunk ck (0..15): jt=ck>>1, half=ck&1, buffer=ck&1.
// Stats accumulate in registers across the whole j-chunk; one
// reduce+atomic set per WG. grid = (8 j-chunks, 128 i-tiles).
template <int PASS>
__global__ __launch_bounds__(256, 2) void pass_kernel(
    const unsigned short* __restrict__ fnb, const float* __restrict__ sq,
    const int* __restrict__ labels,
    float* __restrict__ minpos_d2, float* __restrict__ maxneg_d2,
    float* __restrict__ negsum, float* __restrict__ possum,
    float* __restrict__ poscnt)
{
    __shared__ __align__(16) unsigned short Bs[2][128 * 128];  // 2 x 32 KB

    const int tid  = threadIdx.x;
    const int lane = tid & 63;
    const int wid  = tid >> 6;
    const int wm   = wid >> 1;       // wave row (0..1) -> 32 i-rows
    const int wn   = wid & 1;        // wave col (0..1) -> 64 j-cols
    const int q    = lane >> 4;
    const int c16  = lane & 15;
    const int i0    = blockIdx.y * 64;
    const int jbase = blockIdx.x * 1024;

    // ---- A fragments -> registers (A layout: [m=lane&15][k=q*8+j]) ----
    bf16x8 af[2][8];
    #pragma unroll
    for (int mt = 0; mt < 2; ++mt) {
        const unsigned short* arow =
            fnb + (size_t)(i0 + wm * 32 + mt * 16 + c16) * ND;
        #pragma unroll
        for (int kb = 0; kb < 8; ++kb)
            af[mt][kb] = *(const bf16x8*)(arow + kb * 32 + q * 8);
    }

    // stage chunk ck: rows of j-tile ck>>1, k-half ck&1, into Bs[ck&1].
    // Row = 256 B = 16 chunks of 16 B; LDS slot sc holds global chunk
    // (sc&8)|((sc^r)&7)  (XOR on global side; frag reads stay 2-way/free).
    // Wave w covers rows [w*32, w*32+32); inst t: 4 rows (1 KB).
    auto stageB = [&](int ck) {
        const int jt = ck >> 1, half = ck & 1;
        const unsigned short* src =
            fnb + (size_t)(jbase + jt * 128) * ND + half * 128;
        unsigned short* dst = &Bs[half][0];
        #pragma unroll
        for (int t = 0; t < 8; ++t) {
            int rb = wid * 32 + t * 4;
            int r  = rb + (lane >> 4);
            int sc = lane & 15;
            int c  = (sc & 8) | ((sc ^ r) & 7);
            gload_lds16(src + (size_t)r * ND + c * 8, dst + rb * 128);
        }
    };

    // ---- per-lane i-row invariants (8 rows: (k>>2)*16 + q*4 + (k&3)) ----
    int   labi[8]; float sqi[8];
    float mnd2[8], mxd2[8];          // pass 1 accumulators
    float tneg[8], tpos[8];          // pass 2 thresholds (d2 space)
    float ns[8], ps[8], pc[8];       // pass 2 accumulators
    #pragma unroll
    for (int k = 0; k < 8; ++k) {
        int i = i0 + wm * 32 + (k >> 2) * 16 + q * 4 + (k & 3);
        labi[k] = labels[i];
        sqi[k]  = sq[i];
        if (PASS == 1) {
            mnd2[k] = F_INF; mxd2[k] = F_NINF;
        } else {
            float mp = sqrtf(fmaxf(minpos_d2[i], 1e-12f));
            float tn = mp - 0.1f;
            tneg[k] = (tn <= 0.f) ? -3.0f : tn * tn;        // d2 > tneg
            float mx = sqrtf(fmaxf(maxneg_d2[i], 1e-12f));
            float tp = mx + 0.1f;
            tpos[k] = fminf(tp * tp, POS2);                 // d2 < tpos
            ns[k] = 0.f; ps[k] = 0.f; pc[k] = 0.f;
        }
    }

    stageB(0);   // cold prefetch (only un-shadowed drain)

    for (int jt = 0; jt < 8; ++jt) {
        const int j0 = jbase + jt * 128;

        f32x4 acc[2][4];
        #pragma unroll
        for (int mt = 0; mt < 2; ++mt)
            #pragma unroll
            for (int nt = 0; nt < 4; ++nt)
                acc[mt][nt] = (f32x4){0.f, 0.f, 0.f, 0.f};

        int labj[4]; float sqj[4];

        #pragma unroll
        for (int half = 0; half < 2; ++half) {
            __syncthreads();   // drains chunk jt*2+half (issued a phase ago)
            int nck = jt * 2 + half + 1;
            if (nck < 16) stageB(nck);   // prefetch into the other buffer
            if (half == 0) {
                #pragma unroll
                for (int nt = 0; nt < 4; ++nt) {
                    int j = j0 + wn * 64 + nt * 16 + c16;
                    labj[nt] = labels[j];
                    sqj[nt]  = sq[j];
                }
            }
            // compute 4 K=32 steps from Bs[half]
            #pragma unroll
            for (int ks = 0; ks < 4; ++ks) {
                bf16x8 bfr[4];
                #pragma unroll
                for (int nt = 0; nt < 4; ++nt) {
                    int r  = wn * 64 + nt * 16 + c16;
                    int c  = ks * 4 + q;
                    int sc = (c & 8) | ((c ^ r) & 7);
                    bfr[nt] = *(const bf16x8*)(&Bs[half][0] + r * 128 + sc * 8);
                }
                #pragma unroll
                for (int mt = 0; mt < 2; ++mt)
                    #pragma unroll
                    for (int nt = 0; nt < 4; ++nt)
                        acc[mt][nt] = __builtin_amdgcn_mfma_f32_16x16x32_bf16(
                            af[mt][half * 4 + ks], bfr[nt], acc[mt][nt], 0, 0, 0);
            }
        }

        // ---- per-tile epilogue: accumulate into register stats ----
        #pragma unroll
        for (int mt = 0; mt < 2; ++mt) {
            #pragma unroll
            for (int reg = 0; reg < 4; ++reg) {
                int k = mt * 4 + reg;
                #pragma unroll
                for (int nt = 0; nt < 4; ++nt) {
                    float dot = acc[mt][nt][reg];
                    float d2  = fmaf(-2.0f, dot, sqi[k] + sqj[nt]);
                    bool same = (labi[k] == labj[nt]);
                    if (PASS == 1) {
                        bool p = same && (d2 < POS2);
                        mnd2[k] = fminf(mnd2[k], p ? d2 : F_INF);
                        mxd2[k] = fmaxf(mxd2[k], same ? F_NINF : d2);
                    } else {
                        float dist = sqrtf(fmaxf(d2, 1e-12f));
                        bool tkp = same && (d2 < tpos[k]);
                        bool tkn = !same && (d2 > tneg[k]);
                        float arg = fmaf(same ? 2.0f : -40.0f, dist,
                                         same ? -1.4f : 40.0f);
                        float e = __expf(arg);
                        ps[k] += tkp ? e : 0.f;
                        ns[k] += tkn ? e : 0.f;
                        pc[k] += tkp ? 1.f : 0.f;
                    }
                }
            }
        }
    }

    // ---- once per WG: reduce across the 16 c16 lanes, then atomics ----
    #pragma unroll
    for (int k = 0; k < 8; ++k) {
        int i = i0 + wm * 32 + (k >> 2) * 16 + q * 4 + (k & 3);
        if (PASS == 1) {
            #pragma unroll
            for (int off = 8; off > 0; off >>= 1) {
                mnd2[k] = fminf(mnd2[k], __shfl_xor(mnd2[k], off, 64));
                mxd2[k] = fmaxf(mxd2[k], __shfl_xor(mxd2[k], off, 64));
            }
            if (c16 == 0) {
                // at most one sub-zero candidate per row (the diagonal),
                // so int ordering == float ordering for the winner
                atomicMin((int*)&minpos_d2[i], __float_as_int(mnd2[k]));
                atomicMax((int*)&maxneg_d2[i], __float_as_int(mxd2[k]));
            }
        } else {
            #pragma unroll
            for (int off = 8; off > 0; off >>= 1) {
                ns[k] += __shfl_xor(ns[k], off, 64);
                ps[k] += __shfl_xor(ps[k], off, 64);
                pc[k] += __shfl_xor(pc[k], off, 64);
            }
            if (c16 == 0) {
                atomicAdd(&negsum[i], ns[k]);
                atomicAdd(&possum[i], ps[k]);
                atomicAdd(&poscnt[i], pc[k]);
            }
        }
    }
}

// ------------------------------------------------------------- finalize
__global__ void finalize_kernel(const float* __restrict__ negsum,
                                const float* __restrict__ possum,
                                const float* __restrict__ poscnt,
                                float* out) {
    int i = blockIdx.x * 256 + threadIdx.x;
    float v = 0.f;
    if (i < NB) {
        // each neg term >= e^-40 > 0, so negsum>0 <=> neg count >= 1
        bool valid = (negsum[i] > 0.f) && (poscnt[i] >= 0.5f);
        if (valid) {
            float nl = log1pf(negsum[i]) * (1.0f / 40.0f);
            float pl = log1pf(possum[i]) / (poscnt[i] + 1e-5f);
            v = nl + pl;
        }
    }
    #pragma unroll
    for (int off = 32; off > 0; off >>= 1) v += __shfl_xor(v, off, 64);
    __shared__ float red[4];
    if ((threadIdx.x & 63) == 0) red[threadIdx.x >> 6] = v;
    __syncthreads();
    if (threadIdx.x == 0)
        atomicAdd(out, (red[0] + red[1] + red[2] + red[3]) * (1.0f / NB));
}

// ------------------------------------------------------------ launcher
extern "C" void kernel_launch(void* const* d_in, const int* in_sizes, int n_in,
                              void* d_out, int out_size, void* d_ws, size_t ws_size,
                              hipStream_t stream) {
    const float* feats  = (const float*)d_in[0];
    const int*   labels = (const int*)d_in[1];
    float* out = (float*)d_out;

    // workspace: fnb bf16[NB*ND] (4 MB) then fp32 row arrays
    unsigned short* fnb = (unsigned short*)d_ws;
    float* sqv       = (float*)(fnb + (size_t)NB * ND);
    float* minpos_d2 = sqv + NB;
    float* maxneg_d2 = minpos_d2 + NB;
    float* negsum    = maxneg_d2 + NB;
    float* possum    = negsum + NB;
    float* poscnt    = possum + NB;

    normalize_kernel<<<NB / 4, 256, 0, stream>>>(feats, fnb, sqv, minpos_d2,
                                                 maxneg_d2, negsum, possum,
                                                 poscnt, out);

    dim3 grid(NB / 1024, NB / 64);   // (8 j-chunks, 128 i-tiles)
    pass_kernel<1><<<grid, 256, 0, stream>>>(fnb, sqv, labels, minpos_d2,
                                             maxneg_d2, negsum, possum, poscnt);
    pass_kernel<2><<<grid, 256, 0, stream>>>(fnb, sqv, labels, minpos_d2,
                                             maxneg_d2, negsum, possum, poscnt);
    finalize_kernel<<<NB / 256, 256, 0, stream>>>(negsum, possum, poscnt, out);
}